// Round 6
// baseline (129.135 us; speedup 1.0000x reference)
//
#include <hip/hip_runtime.h>
#include <cstdint>

#define TDIM 8192   // B_*S_ = 4*2048 flattened tokens
#define MDIM 1024   // in_features (GEMM K)
#define NDIM 1024   // out_features
#define KBITS 8
#define BK 64       // K-depth per staging iteration
#define TT 64       // t-tile (rows)
#define TN 128      // n-tile (cols)

typedef __bf16 bf16x8 __attribute__((ext_vector_type(8)));
typedef float f32x4 __attribute__((ext_vector_type(4)));
typedef float f32x16 __attribute__((ext_vector_type(16)));

#define GAS(p) ((__attribute__((address_space(1))) void*)(uintptr_t)(p))
#define LAS(p) ((__attribute__((address_space(3))) void*)(uintptr_t)(p))

__device__ __forceinline__ unsigned short f2bf(float f) {
    union { float f; unsigned u; } v; v.f = f;
    unsigned r = v.u + 0x7fffu + ((v.u >> 16) & 1u);  // round-to-nearest-even
    return (unsigned short)(r >> 16);
}

// ---- W-fold: Wt[n][m] = bf16( sum_k scale[k][n] * binary[k][m][n] ) ----
// 32x32 tiles, 1024 blocks (4/CU). Reads coalesced along n, LDS transpose,
// writes coalesced along m. ~36 MB HBM => ~6 us.
__global__ __launch_bounds__(256) void wfold_kernel(const float* __restrict__ binary,
                                                    const float* __restrict__ scale,
                                                    unsigned short* __restrict__ wtr) {
    __shared__ float tile[32][33];
    const int tid = threadIdx.x;
    const int n0 = (blockIdx.x & 31) * 32;
    const int m0 = (blockIdx.x >> 5) * 32;
    const int r = tid >> 3;          // m offset 0..31
    const int cn = (tid & 7) * 4;    // n offset 0..28 step 4
    f32x4 acc = {0.f, 0.f, 0.f, 0.f};
#pragma unroll
    for (int k = 0; k < KBITS; ++k) {
        f32x4 v = *(const f32x4*)(binary + ((size_t)k * MDIM + m0 + r) * NDIM + n0 + cn);
        f32x4 s = *(const f32x4*)(scale + (size_t)k * NDIM + n0 + cn);
        acc += v * s;
    }
#pragma unroll
    for (int e = 0; e < 4; ++e) tile[cn + e][r] = acc[e];
    __syncthreads();
    const int rn = tid >> 3;
    const int cm = (tid & 7) * 4;
    ushort4 o4;
    o4.x = f2bf(tile[rn][cm + 0]);
    o4.y = f2bf(tile[rn][cm + 1]);
    o4.z = f2bf(tile[rn][cm + 2]);
    o4.w = f2bf(tile[rn][cm + 3]);
    *(ushort4*)(wtr + (size_t)(n0 + rn) * MDIM + m0 + cm) = o4;
}

// ---- gemm: out[t][n] = sum_m x[t][m]*Wt[n][m] + bias[n] ----
// A is read DIRECTLY from fp32 x (no bf16 pre-cast pass): staged to LDS as
// fp32 granules (16B = 4 fp32) via global_load_lds, truncation-packed to bf16
// at fragment-read time with v_perm_b32 (1 instr / 2 elems). Removes 50 MB of
// prep HBM traffic. 64x128 tile, BK=64, 1024 blocks (4/CU), 4 waves 2x2,
// wave = 32(t)x64(n) via v_mfma_f32_32x32x16_bf16.
__global__ __launch_bounds__(256, 4) void gemm_kernel(const float* __restrict__ x,
                                                      const unsigned short* __restrict__ wtr,
                                                      const float* __restrict__ bias,
                                                      float* __restrict__ out) {
    __shared__ __attribute__((aligned(16))) float sAf[TT * BK];           // 16 KB fp32
    __shared__ __attribute__((aligned(16))) unsigned short sB[TN * BK];   // 16 KB bf16

    const int tid = threadIdx.x;
    const int lane = tid & 63;
    const int wv = tid >> 6;
    const int wrow = wv >> 1;    // t 32-tile 0..1
    const int wcol = wv & 1;     // n half 0..1
    const int lr = lane & 31;    // row within 32-tile
    const int half = lane >> 5;  // k-half selector

    const int t0 = blockIdx.x * TT;
    const int n0 = blockIdx.y * TN;

    // A staging: 64 rows x 16 fp32-granules (16B=4 f32) = 1024 granules, 4/thread.
    // LDS slot s = r*16+gs holds global granule gs^(r&15) of row r (XOR swizzle).
    const float* srcA[4];
    float* dstA[4];
#pragma unroll
    for (int j = 0; j < 4; ++j) {
        int s = tid + j * 256;
        int r = s >> 4;
        int g = (s & 15) ^ (r & 15);
        srcA[j] = x + (size_t)(t0 + r) * MDIM + g * 4;
        dstA[j] = sAf + s * 4;
    }
    // B staging: 128 rows x 8 bf16-granules (16B=8 bf16) = 1024 granules, 4/thread.
    const unsigned short* srcB[4];
    unsigned short* dstB[4];
#pragma unroll
    for (int j = 0; j < 4; ++j) {
        int s = tid + j * 256;
        int r = s >> 3;
        int g = (s & 7) ^ (r & 7);
        srcB[j] = wtr + (size_t)(n0 + r) * MDIM + g * 8;
        dstB[j] = sB + s * 8;
    }

    // fragment LDS offsets. A (fp32): k16-chunk c, half h needs fp32 granules
    // 4c+2h and 4c+2h+1 of row m, each XOR'd with (m&15). B (bf16): granule
    // 2c+h of row n, XOR'd with (n&7).
    const int mrow = wrow * 32 + lr;
    int a0_off[4], a1_off[4], b_off[4][2];
#pragma unroll
    for (int c = 0; c < 4; ++c) {
        a0_off[c] = mrow * 64 + ((4 * c + 2 * half) ^ (mrow & 15)) * 4;
        a1_off[c] = mrow * 64 + ((4 * c + 2 * half + 1) ^ (mrow & 15)) * 4;
#pragma unroll
        for (int j = 0; j < 2; ++j) {
            int n = wcol * 64 + j * 32 + lr;
            b_off[c][j] = (n * 8 + ((c * 2 + half) ^ (n & 7))) * 8;
        }
    }

    f32x16 acc[2];
#pragma unroll
    for (int j = 0; j < 2; ++j)
#pragma unroll
        for (int r = 0; r < 16; ++r) acc[j][r] = 0.f;

    for (int k0 = 0; k0 < MDIM; k0 += BK) {
#pragma unroll
        for (int j = 0; j < 4; ++j)
            __builtin_amdgcn_global_load_lds(GAS(srcA[j] + k0), LAS(dstA[j]), 16, 0, 0);
#pragma unroll
        for (int j = 0; j < 4; ++j)
            __builtin_amdgcn_global_load_lds(GAS(srcB[j] + k0), LAS(dstB[j]), 16, 0, 0);
        __syncthreads();

#pragma unroll
        for (int c = 0; c < 4; ++c) {
            // A frag: 8 fp32 -> 8 bf16 by truncation pack (hi16 of each fp32).
            f32x4 va = *(const f32x4*)(sAf + a0_off[c]);
            f32x4 vb = *(const f32x4*)(sAf + a1_off[c]);
            union { unsigned u[4]; bf16x8 v; } af;
            union { float f; unsigned u; } e0, e1;
            e0.f = va[0]; e1.f = va[1];
            af.u[0] = __builtin_amdgcn_perm(e1.u, e0.u, 0x07060302);
            e0.f = va[2]; e1.f = va[3];
            af.u[1] = __builtin_amdgcn_perm(e1.u, e0.u, 0x07060302);
            e0.f = vb[0]; e1.f = vb[1];
            af.u[2] = __builtin_amdgcn_perm(e1.u, e0.u, 0x07060302);
            e0.f = vb[2]; e1.f = vb[3];
            af.u[3] = __builtin_amdgcn_perm(e1.u, e0.u, 0x07060302);

            bf16x8 b0 = *(const bf16x8*)(sB + b_off[c][0]);
            bf16x8 b1 = *(const bf16x8*)(sB + b_off[c][1]);
            acc[0] = __builtin_amdgcn_mfma_f32_32x32x16_bf16(af.v, b0, acc[0], 0, 0, 0);
            acc[1] = __builtin_amdgcn_mfma_f32_32x32x16_bf16(af.v, b1, acc[1], 0, 0, 0);
        }
        __syncthreads();
    }

    // epilogue: C/D layout col(n)=lane&31, row(t)=(reg&3)+8*(reg>>2)+4*half. fuse bias.
#pragma unroll
    for (int j = 0; j < 2; ++j) {
        const int n = n0 + wcol * 64 + j * 32 + lr;
        const float bv = bias[n];
#pragma unroll
        for (int r = 0; r < 16; ++r) {
            const int t = t0 + wrow * 32 + (r & 3) + 8 * (r >> 2) + 4 * half;
            out[(size_t)t * NDIM + n] = acc[j][r] + bv;
        }
    }
}

extern "C" void kernel_launch(void* const* d_in, const int* in_sizes, int n_in,
                              void* d_out, int out_size, void* d_ws, size_t ws_size,
                              hipStream_t stream) {
    const float* x      = (const float*)d_in[0];   // [4,2048,1024] fp32
    const float* binary = (const float*)d_in[1];   // [8,1024,1024] fp32 (+/-1)
    const float* scale  = (const float*)d_in[2];   // [8,1,1024] fp32
    const float* bias   = (const float*)d_in[3];   // [1024] fp32
    float* out = (float*)d_out;                    // [4,2048,1024] fp32

    unsigned short* wtr = (unsigned short*)d_ws;   // 2 MB bf16 Wt[n][m]

    wfold_kernel<<<1024, 256, 0, stream>>>(binary, scale, wtr);
    gemm_kernel<<<dim3(TDIM / TT, NDIM / TN), 256, 0, stream>>>(x, wtr, bias, out);
}

// Round 7
// 127.246 us; speedup vs baseline: 1.0148x; 1.0148x over previous
//
#include <hip/hip_runtime.h>
#include <cstdint>

#define TDIM 8192   // B_*S_ = 4*2048 flattened tokens
#define MDIM 1024   // in_features (GEMM K)
#define NDIM 1024   // out_features
#define KBITS 8
#define BK 64       // K-depth per staging iteration
#define TT 128      // t-tile
#define TN 128      // n-tile

typedef __bf16 bf16x8 __attribute__((ext_vector_type(8)));
typedef float f32x4 __attribute__((ext_vector_type(4)));
typedef float f32x16 __attribute__((ext_vector_type(16)));

#define GAS(p) ((__attribute__((address_space(1))) void*)(uintptr_t)(p))
#define LAS(p) ((__attribute__((address_space(3))) void*)(uintptr_t)(p))

__device__ __forceinline__ unsigned short f2bf(float f) {
    union { float f; unsigned u; } v; v.f = f;
    unsigned r = v.u + 0x7fffu + ((v.u >> 16) & 1u);  // round-to-nearest-even
    return (unsigned short)(r >> 16);
}

// ---- fused prep ----
// blocks [0,1024): W-fold 32x32 tiles: Wt[n][m] = bf16(sum_k scale[k][n]*binary[k][m][n])
// blocks [1024,3072): x fp32 -> bf16 in GRANULE-BLOCKED layout
//   xb[tb = t/32][g = k/8][r = t%32][e = k%8]
// so the gemm's A-operand fragment load (lane lr -> row, 8 k-elems) is one
// fully-coalesced 1KB global_load_dwordx4 per wave — A never touches LDS.
__global__ __launch_bounds__(256) void prep_kernel(const float* __restrict__ x,
                                                   unsigned short* __restrict__ xb,
                                                   const float* __restrict__ binary,
                                                   const float* __restrict__ scale,
                                                   unsigned short* __restrict__ wtr) {
    __shared__ float tile[32][33];
    const int tid = threadIdx.x;
    if (blockIdx.x >= 1024) {
        // ---- x cast+repack: block handles tb (32 rows) x 16 k-granules ----
        const int b = blockIdx.x - 1024;
        const int tb = b >> 3;
        const int gchunk = b & 7;
#pragma unroll
        for (int p = 0; p < 2; ++p) {
            const int flat = tid + p * 256;
            const int goff = (flat & 7) | (p << 3);
            const int r = (flat >> 3) & 31;
            const int g = gchunk * 16 + goff;
            const float* src = x + ((size_t)tb * 32 + r) * MDIM + g * 8;
            float4 a = *(const float4*)(src);
            float4 c = *(const float4*)(src + 4);
            uint4 o;
            o.x = (unsigned)f2bf(a.x) | ((unsigned)f2bf(a.y) << 16);
            o.y = (unsigned)f2bf(a.z) | ((unsigned)f2bf(a.w) << 16);
            o.z = (unsigned)f2bf(c.x) | ((unsigned)f2bf(c.y) << 16);
            o.w = (unsigned)f2bf(c.z) | ((unsigned)f2bf(c.w) << 16);
            *(uint4*)(xb + (((size_t)tb * 128 + g) * 32 + r) * 8) = o;
        }
        return;
    }
    // ---- W-fold: 32x32 tile, thread owns (m-row r, 4 consecutive n) ----
    const int n0 = (blockIdx.x & 31) * 32;
    const int m0 = (blockIdx.x >> 5) * 32;
    const int r = tid >> 3;          // m offset 0..31
    const int cn = (tid & 7) * 4;    // n offset 0..28 step 4
    f32x4 acc = {0.f, 0.f, 0.f, 0.f};
#pragma unroll
    for (int k = 0; k < KBITS; ++k) {
        f32x4 v = *(const f32x4*)(binary + ((size_t)k * MDIM + m0 + r) * NDIM + n0 + cn);
        f32x4 s = *(const f32x4*)(scale + (size_t)k * NDIM + n0 + cn);
        acc += v * s;
    }
#pragma unroll
    for (int e = 0; e < 4; ++e) tile[cn + e][r] = acc[e];
    __syncthreads();
    const int rn = tid >> 3;
    const int cm = (tid & 7) * 4;
    ushort4 o4;
    o4.x = f2bf(tile[rn][cm + 0]);
    o4.y = f2bf(tile[rn][cm + 1]);
    o4.z = f2bf(tile[rn][cm + 2]);
    o4.w = f2bf(tile[rn][cm + 3]);
    *(ushort4*)(wtr + (size_t)(n0 + rn) * MDIM + m0 + cm) = o4;
}

// ---- gemm: out[t][n] = sum_m x[t][m]*Wt[n][m] + bias[n] ----
// 128x128 tile, BK=64, 512 blocks (2/CU). Wave = 64(t)x64(n), acc 2x2 f32x16,
// v_mfma_f32_32x32x16_bf16. A fragments load DIRECTLY from granule-blocked xb
// (coalesced 1KB/instr, L1-reused by the sibling wcol wave) — zero A LDS traffic.
// B double-buffered in LDS (2x16KB): one barrier/iter; its vmcnt(0) drain covers
// staging issued a full compute phase earlier. LDS/block-iter: 48KB (was 96KB).
__global__ __launch_bounds__(256) void gemm_kernel(const unsigned short* __restrict__ xb,
                                                   const unsigned short* __restrict__ wtr,
                                                   const float* __restrict__ bias,
                                                   float* __restrict__ out) {
    __shared__ __attribute__((aligned(16))) unsigned short sB[2 * TN * BK];  // 32 KB

    const int tid = threadIdx.x;
    const int lane = tid & 63;
    const int wv = tid >> 6;
    const int wrow = wv >> 1;    // t half (64 rows)
    const int wcol = wv & 1;     // n half (64 cols)
    const int lr = lane & 31;
    const int half = lane >> 5;  // k-half selector

    const int t0 = blockIdx.x * TT;
    const int n0 = blockIdx.y * TN;

    // B staging: 128 rows x 8 granules = 1024 granules (16B), 4/thread.
    // LDS slot s = r*8+gs holds global granule gs^(r&7) of row r (XOR swizzle).
    const unsigned short* srcB[4];
    unsigned short* dstB[4];
#pragma unroll
    for (int j = 0; j < 4; ++j) {
        int s = tid + j * 256;
        int r = s >> 3;
        int g = (s & 7) ^ (r & 7);
        srcB[j] = wtr + (size_t)(n0 + r) * MDIM + g * 8;
        dstB[j] = sB + s * 8;
    }

    // A direct-load base pointers (granule-blocked xb): mtile i, k-granule 'half'
    const unsigned short* aptr[2];
#pragma unroll
    for (int i = 0; i < 2; ++i) {
        size_t tb = (size_t)(t0 >> 5) + wrow * 2 + i;
        aptr[i] = xb + (tb * 128 + half) * 256 + lr * 8;
    }

    // B fragment LDS offsets (within one buffer): k16-chunk c, granule (2c+half)^(n&7)
    int b_off[4][2];
#pragma unroll
    for (int c = 0; c < 4; ++c)
#pragma unroll
        for (int j = 0; j < 2; ++j) {
            int n = wcol * 64 + j * 32 + lr;
            b_off[c][j] = (n * 8 + ((2 * c + half) ^ (n & 7))) * 8;
        }

    f32x16 acc[2][2];
#pragma unroll
    for (int i = 0; i < 2; ++i)
#pragma unroll
        for (int j = 0; j < 2; ++j)
#pragma unroll
            for (int r = 0; r < 16; ++r) acc[i][j][r] = 0.f;

    // prologue: stage B(k=0) into buffer 0
#pragma unroll
    for (int j = 0; j < 4; ++j)
        __builtin_amdgcn_global_load_lds(GAS(srcB[j]), LAS(dstB[j]), 16, 0, 0);
    __syncthreads();

    for (int it = 0; it < MDIM / BK; ++it) {
        const int buf = (it & 1) << 13;     // 0 / 8192 ushorts
        if (it < MDIM / BK - 1) {
            const int nbuf = 8192 - buf;
            const int kof = (it + 1) * BK;
#pragma unroll
            for (int j = 0; j < 4; ++j)
                __builtin_amdgcn_global_load_lds(GAS(srcB[j] + kof), LAS(dstB[j] + nbuf), 16, 0, 0);
        }
        const int aof = it * (BK * 32);     // ushorts per iter in blocked layout
#pragma unroll
        for (int c = 0; c < 4; ++c) {
            bf16x8 a0 = *(const bf16x8*)(aptr[0] + aof + c * 512);
            bf16x8 a1 = *(const bf16x8*)(aptr[1] + aof + c * 512);
            bf16x8 b0 = *(const bf16x8*)(sB + buf + b_off[c][0]);
            bf16x8 b1 = *(const bf16x8*)(sB + buf + b_off[c][1]);
            acc[0][0] = __builtin_amdgcn_mfma_f32_32x32x16_bf16(a0, b0, acc[0][0], 0, 0, 0);
            acc[1][0] = __builtin_amdgcn_mfma_f32_32x32x16_bf16(a1, b0, acc[1][0], 0, 0, 0);
            acc[0][1] = __builtin_amdgcn_mfma_f32_32x32x16_bf16(a0, b1, acc[0][1], 0, 0, 0);
            acc[1][1] = __builtin_amdgcn_mfma_f32_32x32x16_bf16(a1, b1, acc[1][1], 0, 0, 0);
        }
        __syncthreads();
    }

    // epilogue: C/D layout col(n)=lane&31, row(t)=(reg&3)+8*(reg>>2)+4*half. fuse bias.
#pragma unroll
    for (int j = 0; j < 2; ++j) {
        const int n = n0 + wcol * 64 + j * 32 + lr;
        const float bv = bias[n];
#pragma unroll
        for (int i = 0; i < 2; ++i) {
            const int tb = t0 + wrow * 64 + i * 32;
#pragma unroll
            for (int r = 0; r < 16; ++r) {
                const int t = tb + (r & 3) + 8 * (r >> 2) + 4 * half;
                out[(size_t)t * NDIM + n] = acc[i][j][r] + bv;
            }
        }
    }
}

extern "C" void kernel_launch(void* const* d_in, const int* in_sizes, int n_in,
                              void* d_out, int out_size, void* d_ws, size_t ws_size,
                              hipStream_t stream) {
    const float* x      = (const float*)d_in[0];   // [4,2048,1024] fp32
    const float* binary = (const float*)d_in[1];   // [8,1024,1024] fp32 (+/-1)
    const float* scale  = (const float*)d_in[2];   // [8,1,1024] fp32
    const float* bias   = (const float*)d_in[3];   // [1024] fp32
    float* out = (float*)d_out;                    // [4,2048,1024] fp32

    unsigned short* xb  = (unsigned short*)d_ws;            // 16 MB bf16 x (blocked)
    unsigned short* wtr = xb + (size_t)TDIM * MDIM;         // 2 MB bf16 Wt[n][m]

    prep_kernel<<<1024 + 2048, 256, 0, stream>>>(x, xb, binary, scale, wtr);
    gemm_kernel<<<dim3(TDIM / TT, NDIM / TN), 256, 0, stream>>>(xb, wtr, bias, out);
}